// Round 3
// baseline (526.536 us; speedup 1.0000x reference)
//
#include <hip/hip_runtime.h>
#include <hip/hip_bf16.h>

#define ALPHA_ 0.2f
#define EPS_ 1e-12f

typedef short short8 __attribute__((ext_vector_type(8)));
typedef float f32x4 __attribute__((ext_vector_type(4)));

constexpr int BB = 16, KK = 16, DD = 256, NNEG = 16384;
constexpr int ITERS = 6;   // Newton-Schulz iterations (even => final lands in XA)

// ---- workspace layout (float offsets) ---- total 5,309,456 floats = 21.2 MB (proven size)
constexpr size_t OFF_NL1   = 0;         // 1M floats: neg-lo rows 8192..16383 (after Newton)
constexpr size_t OFF_XA_H  = 1048576;   // 512K floats = 1M ushorts
constexpr size_t OFF_XA_L  = 1572864;
constexpr size_t OFF_NH    = 2097152;   // 2M floats: neg-hi (overlays XB/T after Newton)
constexpr size_t OFF_XB_H  = 2097152;
constexpr size_t OFF_XB_L  = 2621440;
constexpr size_t OFF_T_H   = 3145728;
constexpr size_t OFF_T_L   = 3670016;
constexpr size_t OFF_NL0   = 4194304;   // 1M floats: neg-lo rows 0..8191 (overlays S)
constexpr size_t OFF_S_H   = 4194304;
constexpr size_t OFF_S_L   = 4718592;
constexpr size_t OFF_PA_H  = 5242880;   // 65536 ushorts
constexpr size_t OFF_PA_L  = 5275648;
constexpr size_t OFF_BOUND = 5308416;
constexpr size_t OFF_PAP   = 5308432;
constexpr size_t OFF_DPOS2 = 5308688;
constexpr size_t OFF_MINA  = 5308944;
constexpr size_t OFF_MINV  = 5309200;

// ---------- bf16 split helpers (RNE) ----------
__device__ inline unsigned short bf_hi(float x) {
    unsigned u = __float_as_uint(x);
    return (unsigned short)((u + 0x7fffu + ((u >> 16) & 1u)) >> 16);
}
__device__ inline float bf_tof(unsigned short h) { return __uint_as_float(((unsigned)h) << 16); }
__device__ inline void split2(float x, unsigned short& h, unsigned short& l) {
    h = bf_hi(x); l = bf_hi(x - bf_tof(h));
}

// ---------- spectral bound per batch: scale = 2/(1+B) ----------
__global__ __launch_bounds__(256) void kbound(const float* __restrict__ Sig, float* __restrict__ ws) {
    int b = blockIdx.x, t = threadIdx.x;
    const float* S = Sig + (size_t)b * DD * DD;
    __shared__ float v[DD];
    __shared__ float red[256];
    float cs = 0.f;
    for (int i = 0; i < DD; ++i) cs += fabsf(S[i * DD + t]);
    red[t] = cs; __syncthreads();
    for (int s = 128; s > 0; s >>= 1) { if (t < s) red[t] = fmaxf(red[t], red[t + s]); __syncthreads(); }
    float G = red[0]; __syncthreads();
    v[t] = 1.f; __syncthreads();
    for (int it = 0; it < 12; ++it) {
        float w = 0.f;
        for (int i = 0; i < DD; ++i) w = fmaf(S[i * DD + t], v[i], w);
        red[t] = w * w; __syncthreads();
        for (int s = 128; s > 0; s >>= 1) { if (t < s) red[t] += red[t + s]; __syncthreads(); }
        float nrm = sqrtf(red[0]); __syncthreads();
        v[t] = w / nrm; __syncthreads();
    }
    float w2 = 0.f;
    for (int i = 0; i < DD; ++i) w2 = fmaf(S[i * DD + t], v[i], w2);
    red[t] = w2 * v[t]; __syncthreads();
    for (int s = 128; s > 0; s >>= 1) { if (t < s) red[t] += red[t + s]; __syncthreads(); }
    if (t == 0) {
        float lam = red[0];
        float Bb = fminf(G, 1.06f * lam + 0.05f);
        ws[OFF_BOUND + b] = 2.f / (1.f + Bb);
    }
}

// ---------- fp32 -> bf16 hi/lo split for Sigma ----------
__global__ __launch_bounds__(256) void ksplitS(const float* __restrict__ in,
                                               unsigned short* __restrict__ h,
                                               unsigned short* __restrict__ l, int n) {
    int i = blockIdx.x * 256 + threadIdx.x;
    if (i < n) { unsigned short hh, ll; split2(in[i], hh, ll); h[i] = hh; l[i] = ll; }
}

// ---------- X0 = scale * I (split) ----------
__global__ __launch_bounds__(256) void kinitx(float* __restrict__ ws) {
    int idx = blockIdx.x * 256 + threadIdx.x;     // < 16*65536
    int b = idx >> 16, r = (idx >> 8) & 255, c = idx & 255;
    float s = ws[OFF_BOUND + b];
    float v = (r == c) ? s : 0.f;
    unsigned short h, l; split2(v, h, l);
    ((unsigned short*)(ws + OFF_XA_H))[idx] = h;
    ((unsigned short*)(ws + OFF_XA_L))[idx] = l;
}

// ---------- batched 256x256 MFMA split GEMM (operands symmetric: B-frags read rows) ----------
__global__ __launch_bounds__(256, 1) void gemm_mfma(const unsigned short* __restrict__ Ah,
                                                    const unsigned short* __restrict__ Al,
                                                    const unsigned short* __restrict__ Bh,
                                                    const unsigned short* __restrict__ Bl,
                                                    unsigned short* __restrict__ Ch,
                                                    unsigned short* __restrict__ Cl, int mode2i) {
    int b = blockIdx.y;
    int i0 = (blockIdx.x & 3) * 64, j0 = (blockIdx.x >> 2) * 64;
    size_t base = (size_t)b * 65536;
    int t = threadIdx.x, lane = t & 63, wid = t >> 6;
    int wm = wid & 1, wf = wid >> 1;
    int l15 = lane & 15, lg = lane >> 4;
    f32x4 acc[2][2] = {};
    int arow0 = i0 + wm * 32 + l15;
    int bcol0 = j0 + wf * 32 + l15;
    #pragma unroll
    for (int e0 = 0; e0 < 256; e0 += 32) {
        int eoff = e0 + 8 * lg;
        short8 a_h[2], a_l[2], b_h[2], b_l[2];
        #pragma unroll
        for (int m = 0; m < 2; ++m) {
            size_t off = base + (size_t)(arow0 + m * 16) * 256 + eoff;
            a_h[m] = *reinterpret_cast<const short8*>(Ah + off);
            a_l[m] = *reinterpret_cast<const short8*>(Al + off);
        }
        #pragma unroll
        for (int n = 0; n < 2; ++n) {
            size_t off = base + (size_t)(bcol0 + n * 16) * 256 + eoff;  // symmetric: row == col
            b_h[n] = *reinterpret_cast<const short8*>(Bh + off);
            b_l[n] = *reinterpret_cast<const short8*>(Bl + off);
        }
        #pragma unroll
        for (int m = 0; m < 2; ++m)
            #pragma unroll
            for (int n = 0; n < 2; ++n) {
                acc[m][n] = __builtin_amdgcn_mfma_f32_16x16x32_bf16(a_h[m], b_h[n], acc[m][n], 0, 0, 0);
                acc[m][n] = __builtin_amdgcn_mfma_f32_16x16x32_bf16(a_h[m], b_l[n], acc[m][n], 0, 0, 0);
                acc[m][n] = __builtin_amdgcn_mfma_f32_16x16x32_bf16(a_l[m], b_h[n], acc[m][n], 0, 0, 0);
            }
    }
    #pragma unroll
    for (int m = 0; m < 2; ++m)
        #pragma unroll
        for (int n = 0; n < 2; ++n)
            #pragma unroll
            for (int r = 0; r < 4; ++r) {
                int row = i0 + wm * 32 + m * 16 + 4 * lg + r;   // C: col=lane&15, row=(lane>>4)*4+r
                int col = j0 + wf * 32 + n * 16 + l15;
                float v = acc[m][n][r];
                if (mode2i) v = ((row == col) ? 2.f : 0.f) - v;
                unsigned short h, l; split2(v, h, l);
                size_t off = base + (size_t)row * 256 + col;
                Ch[off] = h; Cl[off] = l;
            }
}

// ---------- negatives pre-split (once) + min-buffer init ----------
__global__ __launch_bounds__(256) void knegsplit(const float* __restrict__ negs,
                                                 unsigned short* __restrict__ NH,
                                                 unsigned short* __restrict__ NL0,
                                                 unsigned short* __restrict__ NL1,
                                                 unsigned* __restrict__ mina,
                                                 unsigned* __restrict__ minv) {
    size_t i8 = ((size_t)blockIdx.x * 256 + threadIdx.x) * 8;   // grid covers 16384*256/8
    f32x4 v0 = *reinterpret_cast<const f32x4*>(negs + i8);
    f32x4 v1 = *reinterpret_cast<const f32x4*>(negs + i8 + 4);
    short8 h, l;
    #pragma unroll
    for (int j = 0; j < 4; ++j) {
        unsigned short hh, ll;
        split2(v0[j], hh, ll); h[j] = (short)hh; l[j] = (short)ll;
        split2(v1[j], hh, ll); h[4 + j] = (short)hh; l[4 + j] = (short)ll;
    }
    *reinterpret_cast<short8*>(NH + i8) = h;
    unsigned short* NL = (i8 < (size_t)8192 * 256) ? (NL0 + i8) : (NL1 + i8 - (size_t)8192 * 256);
    *reinterpret_cast<short8*>(NL) = l;
    if (blockIdx.x == 0) {
        mina[threadIdx.x] = 0x7f800000u; minv[threadIdx.x] = 0x7f800000u;
    }
}

// ---------- per (b,k): PA row (split), pAp, dpos2 ----------
__global__ __launch_bounds__(256) void k2(const float* __restrict__ Z1, const float* __restrict__ Z2,
                                          const int* __restrict__ match,
                                          const unsigned short* __restrict__ AH,
                                          const unsigned short* __restrict__ AL,
                                          float* __restrict__ ws) {
    int bk = blockIdx.x; int b = bk >> 4; int t = threadIdx.x;
    const unsigned short* Ah = AH + (size_t)b * 65536;
    const unsigned short* Al = AL + (size_t)b * 65536;
    __shared__ float z[DD], df[DD];
    __shared__ float red[256];
    int m = match[bk];
    float zv = Z1[(size_t)bk * DD + t];
    float qv = Z2[((size_t)b * KK + m) * DD + t];
    z[t] = zv; df[t] = zv - qv;
    __syncthreads();
    float pa = 0.f, da = 0.f;
    for (int e = 0; e < DD; ++e) {
        float Ae = bf_tof(Ah[(size_t)e * 256 + t]) + bf_tof(Al[(size_t)e * 256 + t]);
        pa = fmaf(z[e], Ae, pa);
        da = fmaf(df[e], Ae, da);
    }
    unsigned short ph, pl; split2(pa, ph, pl);
    ((unsigned short*)(ws + OFF_PA_H))[(size_t)bk * 256 + t] = ph;   // PA[b][k][e]
    ((unsigned short*)(ws + OFF_PA_L))[(size_t)bk * 256 + t] = pl;
    float dfv = df[t];
    red[t] = pa * zv; __syncthreads();
    for (int s = 128; s > 0; s >>= 1) { if (t < s) red[t] += red[t + s]; __syncthreads(); }
    float pAp = red[0]; __syncthreads();
    red[t] = da * dfv; __syncthreads();
    for (int s = 128; s > 0; s >>= 1) { if (t < s) red[t] += red[t + s]; __syncthreads(); }
    if (t == 0) {
        ws[OFF_PAP + bk]   = pAp;
        ws[OFF_DPOS2 + bk] = fmaxf(red[0], EPS_);
    }
}

// ---------- main kernel: direct-global MFMA  N @ [A | PA^T]  + fused nAn rowsum + semi-hard mins ----------
// No LDS / no barriers in main loop. 4 waves (wm x wf = 2x2), n-tile 128, f-range 272.
__global__ __launch_bounds__(256, 2) void k3(const float* __restrict__ negs,
                                             const unsigned short* __restrict__ Ahi,
                                             const unsigned short* __restrict__ Alo,
                                             const unsigned short* __restrict__ PAh,
                                             const unsigned short* __restrict__ PAl,
                                             const unsigned short* __restrict__ NH,
                                             const unsigned short* __restrict__ NL0,
                                             const unsigned short* __restrict__ NL1,
                                             const float* __restrict__ pap,
                                             const float* __restrict__ dpos2,
                                             unsigned* __restrict__ mina,
                                             unsigned* __restrict__ minv) {
    __shared__ float smem[7168];   // epilogue only
    int lin = blockIdx.x;
    int b  = (lin & 7) * 2 + ((lin >> 3) & 1);      // XCD-aware: 2 b-values per XCD
    int n0 = (lin >> 4) * 128;
    int t = threadIdx.x, lane = t & 63, wid = t >> 6;
    int wm = wid & 1, wf = wid >> 1;
    int l15 = lane & 15, lg = lane >> 4;
    const unsigned short* Ab  = Ahi + (size_t)b * 65536;
    const unsigned short* Al_ = Alo + (size_t)b * 65536;
    const unsigned short* Ph  = PAh + (size_t)b * 4096;
    const unsigned short* Pl  = PAl + (size_t)b * 4096;
    const unsigned short* Nh  = NH + (size_t)n0 * 256;
    const unsigned short* Nl  = (n0 < 8192) ? (NL0 + (size_t)n0 * 256)
                                            : (NL1 + (size_t)(n0 - 8192) * 256);
    f32x4 acc[4][9] = {};
    #pragma unroll 2
    for (int e0 = 0; e0 < 256; e0 += 32) {
        int eo = e0 + 8 * lg;
        short8 ah[4], al[4];
        #pragma unroll
        for (int m = 0; m < 4; ++m) {
            size_t off = (size_t)(wm * 64 + m * 16 + l15) * 256 + eo;
            ah[m] = *reinterpret_cast<const short8*>(Nh + off);
            al[m] = *reinterpret_cast<const short8*>(Nl + off);
        }
        #pragma unroll
        for (int ff = 0; ff < 9; ++ff) {
            if (ff == 8 && wf == 1) continue;        // f >= 272
            const unsigned short* bhp;
            const unsigned short* blp;
            if (ff == 7 && wf == 1) {                // PA rows 256..271
                bhp = Ph + (size_t)l15 * 256 + eo;
                blp = Pl + (size_t)l15 * 256 + eo;
            } else {
                size_t off = (size_t)(wf * 144 + ff * 16 + l15) * 256 + eo;
                bhp = Ab + off; blp = Al_ + off;
            }
            short8 bh = *reinterpret_cast<const short8*>(bhp);
            short8 bl = *reinterpret_cast<const short8*>(blp);
            #pragma unroll
            for (int m = 0; m < 4; ++m) {
                acc[m][ff] = __builtin_amdgcn_mfma_f32_16x16x32_bf16(ah[m], bh, acc[m][ff], 0, 0, 0);
                acc[m][ff] = __builtin_amdgcn_mfma_f32_16x16x32_bf16(ah[m], bl, acc[m][ff], 0, 0, 0);
                acc[m][ff] = __builtin_amdgcn_mfma_f32_16x16x32_bf16(al[m], bh, acc[m][ff], 0, 0, 0);
            }
        }
    }
    // ---- epilogue: nAn = rowsum(Y .* N) over f<256; pAn from PA frag (wf1, ff=7) ----
    float* pAn_l = smem;            // [128][17]
    float* nAnp  = smem + 2176;     // [2][128][17]
    float* nAn_l = smem + 6528;     // [128]
    float* reda  = smem + 6656;     // [256]
    float* redv  = smem + 6912;     // [256]

    #pragma unroll
    for (int m = 0; m < 4; ++m) {
        #pragma unroll
        for (int r = 0; r < 4; ++r) {
            int nl = wm * 64 + m * 16 + 4 * lg + r;     // C: row=(lane>>4)*4+r
            int n  = n0 + nl;
            float s = 0.f;
            #pragma unroll
            for (int ff = 0; ff < 9; ++ff) {
                int fb = wf * 144 + ff * 16;
                if (fb < 256) {                          // excludes PA frag & beyond
                    float w = negs[(size_t)n * 256 + fb + l15];
                    s = fmaf(acc[m][ff][r], w, s);
                }
            }
            nAnp[(wf * 128 + nl) * 17 + l15] = s;
            if (wf == 1) pAn_l[nl * 17 + l15] = acc[m][7][r];   // f = 256 + (lane&15) => k
        }
    }
    __syncthreads();
    if (t < 128) {
        float s = 0.f;
        #pragma unroll
        for (int x = 0; x < 16; ++x) s += nAnp[t * 17 + x] + nAnp[(128 + t) * 17 + x];
        nAn_l[t] = s;
    }
    __syncthreads();
    int tx = t & 15, ty = t >> 4;
    float pApk = pap[b * 16 + tx];
    float dp2  = dpos2[b * 16 + tx];
    float mn_a = __uint_as_float(0x7f800000u), mn_v = mn_a;
    #pragma unroll
    for (int ii = 0; ii < 8; ++ii) {
        int n = ty * 8 + ii;
        float d2v = pApk - 2.f * pAn_l[n * 17 + tx] + nAn_l[n];
        float c = fmaxf(d2v, EPS_);
        mn_a = fminf(mn_a, c);
        if (c > dp2) mn_v = fminf(mn_v, c);
    }
    reda[ty * 16 + tx] = mn_a; redv[ty * 16 + tx] = mn_v;
    __syncthreads();
    if (ty == 0) {
        float ra = reda[tx], rv = redv[tx];
        #pragma unroll
        for (int y = 1; y < 16; ++y) {
            ra = fminf(ra, reda[y * 16 + tx]);
            rv = fminf(rv, redv[y * 16 + tx]);
        }
        atomicMin(&mina[b * 16 + tx], __float_as_uint(ra));
        atomicMin(&minv[b * 16 + tx], __float_as_uint(rv));
    }
}

// ---------- final loss ----------
__global__ __launch_bounds__(256) void k5(const float* __restrict__ dpos2,
                                          const unsigned* __restrict__ mina,
                                          const unsigned* __restrict__ minv,
                                          float* __restrict__ out) {
    int t = threadIdx.x;
    __shared__ float red[256];
    float dp = sqrtf(dpos2[t]);
    unsigned mv = minv[t], ma = mina[t];
    unsigned sel = (mv < 0x7f800000u) ? mv : ma;
    float dn = sqrtf(__uint_as_float(sel));
    red[t] = fmaxf(dp - dn + ALPHA_, 0.f);
    __syncthreads();
    for (int s = 128; s > 0; s >>= 1) { if (t < s) red[t] += red[t + s]; __syncthreads(); }
    if (t == 0) out[0] = red[0] * (1.f / 256.f);
}

extern "C" void kernel_launch(void* const* d_in, const int* in_sizes, int n_in,
                              void* d_out, int out_size, void* d_ws, size_t ws_size,
                              hipStream_t stream) {
    (void)in_sizes; (void)n_in; (void)out_size; (void)ws_size;
    const float* Z1   = (const float*)d_in[0];
    const float* Z2   = (const float*)d_in[1];
    const int*   mat  = (const int*)d_in[2];
    const float* negs = (const float*)d_in[3];
    const float* Sig  = (const float*)d_in[4];
    float* ws = (float*)d_ws;
    unsigned short* S_H  = (unsigned short*)(ws + OFF_S_H);
    unsigned short* S_L  = (unsigned short*)(ws + OFF_S_L);
    unsigned short* XA_H = (unsigned short*)(ws + OFF_XA_H);
    unsigned short* XA_L = (unsigned short*)(ws + OFF_XA_L);
    unsigned short* XB_H = (unsigned short*)(ws + OFF_XB_H);
    unsigned short* XB_L = (unsigned short*)(ws + OFF_XB_L);
    unsigned short* T_H  = (unsigned short*)(ws + OFF_T_H);
    unsigned short* T_L  = (unsigned short*)(ws + OFF_T_L);
    unsigned short* PA_H = (unsigned short*)(ws + OFF_PA_H);
    unsigned short* PA_L = (unsigned short*)(ws + OFF_PA_L);
    unsigned short* NH   = (unsigned short*)(ws + OFF_NH);
    unsigned short* NL0  = (unsigned short*)(ws + OFF_NL0);
    unsigned short* NL1  = (unsigned short*)(ws + OFF_NL1);
    unsigned* mina = (unsigned*)(ws + OFF_MINA);
    unsigned* minv = (unsigned*)(ws + OFF_MINV);
    float* out = (float*)d_out;

    kbound<<<BB, 256, 0, stream>>>(Sig, ws);
    ksplitS<<<4096, 256, 0, stream>>>(Sig, S_H, S_L, BB * DD * DD);
    kinitx<<<4096, 256, 0, stream>>>(ws);

    unsigned short* pah = XA_H; unsigned short* pal = XA_L;
    unsigned short* pbh = XB_H; unsigned short* pbl = XB_L;
    for (int it = 0; it < ITERS; ++it) {
        gemm_mfma<<<dim3(16, BB), 256, 0, stream>>>(S_H, S_L, pah, pal, T_H, T_L, 1);   // T = 2I - S@X
        gemm_mfma<<<dim3(16, BB), 256, 0, stream>>>(pah, pal, T_H, T_L, pbh, pbl, 0);   // X' = X@T
        unsigned short* th = pah; pah = pbh; pbh = th;
        unsigned short* tl = pal; pal = pbl; pbl = tl;
    }
    // ITERS even => final split inverse in XA_H/XA_L; XB/T/S regions now dead

    knegsplit<<<NNEG * DD / 8 / 256, 256, 0, stream>>>(negs, NH, NL0, NL1, mina, minv);
    k2<<<BB * KK, 256, 0, stream>>>(Z1, Z2, mat, XA_H, XA_L, ws);
    k3<<<BB * NNEG / 128, 256, 0, stream>>>(negs, XA_H, XA_L, PA_H, PA_L, NH, NL0, NL1,
                                            ws + OFF_PAP, ws + OFF_DPOS2, mina, minv);
    k5<<<1, 256, 0, stream>>>(ws + OFF_DPOS2, mina, minv, out);
}